// Round 7
// baseline (3709.383 us; speedup 1.0000x reference)
//
#include <hip/hip_runtime.h>
#include <math.h>

typedef __attribute__((ext_vector_type(8))) short s8v;
typedef __attribute__((ext_vector_type(8))) _Float16 h8v;
typedef __attribute__((ext_vector_type(4))) float f4v;

#define L2E 1.44269504089f
#define INV2048 4.8828125e-4f
__device__ __forceinline__ float fexp2(float x) { return __builtin_amdgcn_exp2f(x); }
__device__ __forceinline__ float frcp(float x)  { return __builtin_amdgcn_rcpf(x); }
__device__ __forceinline__ float fsigm(float x) { return frcp(1.0f + fexp2(-L2E * x)); }
__device__ __forceinline__ float ftanh_(float x){ return 1.0f - 2.0f * frcp(fexp2((2.0f*L2E) * x) + 1.0f); }
__device__ __forceinline__ float rdl(float v, int l) {
    return __uint_as_float(__builtin_amdgcn_readlane(__float_as_uint(v), l));
}
#define WFENCE() asm volatile("s_waitcnt lgkmcnt(0)" ::: "memory")

// fp16 scaled split: x ~= hi + lo/2048, lo kept in normal fp16 range (flush-proof).
__device__ __forceinline__ void hsplit(float x, unsigned short& hi, unsigned short& lo) {
    _Float16 h = (_Float16)x;
    _Float16 l = (_Float16)((x - (float)h) * 2048.0f);
    hi = __builtin_bit_cast(unsigned short, h);
    lo = __builtin_bit_cast(unsigned short, l);
}
__device__ __forceinline__ float hjoin(unsigned short hi, unsigned short lo) {
    return (float)__builtin_bit_cast(_Float16, hi)
         + (float)__builtin_bit_cast(_Float16, lo) * INV2048;
}
__device__ __forceinline__ f4v mfmah(s8v a, s8v b, f4v c) {
    return __builtin_amdgcn_mfma_f32_16x16x32_f16(
        __builtin_bit_cast(h8v, a), __builtin_bit_cast(h8v, b), c, 0, 0, 0);
}

// ---------- prologue: gcn1/gcn2/dec1 B-fragments (fp16 hi / scaled-lo) into d_ws ----------
// ws layout in s8v (16B) units — MUST match stgnn consumption:
//   gcn1hi [0,512) gcn1lo [512,1024) gcn2hi [1024,1536) gcn2lo [1536,2048)
//   dechi [2048,2304) declo [2304,2560)
// R5/R6 BUG (fixed): staging used g*16384 shorts (s8v 2048) and dec base 32768 shorts
// (s8v 4096) — gcn2 read re-poisoned 0xAA (=> s2 == 0), dec1 read gcn2 data.
__global__ void build_ws(const float* __restrict__ g1w, const float* __restrict__ g2w,
                         const float* __restrict__ d1w, unsigned short* __restrict__ ws)
{
    int tid = threadIdx.x;  // 256
    for (int u = tid; u < 1024; u += 256) {       // gcn frags: B[k][n] = W[k*64+n]
        int g = u >> 9, s = (u >> 6) & 7, ln = u & 63;
        int nt = s >> 1, ks = s & 1;
        int n = nt * 16 + (ln & 15);
        int k0 = ks * 32 + ((ln >> 4) & 3) * 8;
        const float* W = g ? g2w : g1w;
        unsigned short* dh = ws + (size_t)g * 8192 + ((size_t)(s * 64 + ln)) * 8;
        #pragma unroll
        for (int j = 0; j < 8; ++j) {
            unsigned short h, l;
            hsplit(W[(k0 + j) * 64 + n], h, l);
            dh[j] = h; dh[4096 + j] = l;
        }
    }
    for (int u = tid; u < 256; u += 256) {        // dec1 frags: B[k][j] = d1w[k*32+j]
        int s = u >> 6, ln = u & 63;
        int nt = s >> 1, ks = s & 1;
        int n = nt * 16 + (ln & 15);
        int k0 = ks * 32 + ((ln >> 4) & 3) * 8;
        unsigned short* dh = ws + 16384 + ((size_t)(s * 64 + ln)) * 8;
        #pragma unroll
        for (int j = 0; j < 8; ++j) {
            unsigned short h, l;
            hsplit(d1w[(k0 + j) * 32 + n], h, l);
            dh[j] = h; dh[2048 + j] = l;
        }
    }
}

// ---------- main kernel: one wave = one batch, fp16-split MFMA everywhere ----------
__global__ __launch_bounds__(512, 2)
void stgnn(const float* __restrict__ xh,   const float* __restrict__ adj,
           const float* __restrict__ encw, const float* __restrict__ encb,
           const float* __restrict__ g1b,  const float* __restrict__ g2b,
           const float* __restrict__ wih,  const float* __restrict__ whh,
           const float* __restrict__ bih,  const float* __restrict__ bhh,
           const float* __restrict__ d1b,  const float* __restrict__ d2w,
           const float* __restrict__ d2b,  const unsigned short* __restrict__ ws,
           float* __restrict__ out)
{
    // LDS 160 KiB. Per-wave act region (shorts, 1792 each, bytes [wv*3584, +3584)):
    //   RsHi [0,448) RsLo [448,896) RhHi [896,1344) RhLo [1344,1792), rows n<7 stride 64.
    //   fw = float view of the SAME region (adj scratch + dec1 output; Rs dead then).
    // gapf floats [7168,7808) = per-wave pred scratch.
    // gate frags shorts [16384,81920): WIHI WILO WHHI WHLO (16384 each).
    __shared__ float pool[40960];
    unsigned short* sp = (unsigned short*)pool;

    const int tid  = threadIdx.x;
    const int lane = tid & 63;
    const int wv   = tid >> 6;
    const int q    = lane >> 4;
    const int c15  = lane & 15;
    const int batch = blockIdx.x * 8 + wv;

    // ---- stage gate-weight B-fragments (fp16 split + swizzled), block-cooperative ----
    for (int it = 0; it < 8; ++it) {
        int idx = tid + it * 512;                  // 0..4095
        int ln = idx & 63, slot = idx >> 6;        // slot: mat(1)|nt(4)|ks(1)
        int mat = slot >> 5, nt = (slot >> 1) & 15, ks = slot & 1;
        int col = nt * 16 + (ln & 15);
        int k0 = ks * 32 + ((ln >> 4) & 3) * 8;
        const float* src = (mat ? whh : wih) + col * 64 + k0;   // k-contiguous
        unsigned short* dh = sp + 16384 + mat * 32768 + (size_t)((nt * 2 + ks) * 64 + ln) * 8;
        #pragma unroll
        for (int j = 0; j < 8; ++j) {
            unsigned short h, l;
            hsplit(src[j], h, l);
            dh[j] = h; dh[16384 + j] = l;
        }
    }

    unsigned short* aw = sp + wv * 1792;       // own act region (shorts)
    float* fw = (float*)aw;                    // float view of the SAME region
    float* gapf = pool + 7168 + wv * 80;       // persistent pred scratch

    // ---- biases ----
    float benc = encb[lane];
    float bg1v[4], bg2v[4], bdec[2], biasg[16];
    #pragma unroll
    for (int i = 0; i < 4; ++i) { bg1v[i] = g1b[i * 16 + c15]; bg2v[i] = g2b[i * 16 + c15]; }
    #pragma unroll
    for (int i = 0; i < 2; ++i) bdec[i] = d1b[i * 16 + c15];
    #pragma unroll
    for (int i = 0; i < 16; ++i) biasg[i] = bih[i * 16 + c15] + bhh[i * 16 + c15];
    const int dn = lane / 6, dd = lane - dn * 6;          // dec2 mapping (lane<42)
    float bd2 = d2b[lane < 42 ? dd : 0];
    const int lf0 = lane - (lane / 11) * 11;              // f for xr0 flat=lane
    const bool u0 = lf0 < 6;
    const bool u1 = (lane >= 2) && (lane < 8);            // xr1 flat=64+lane dyn

    // ---- adjacency normalize (wave-local, own-region float scratch) ----
    if (lane < 49) {
        int ai = lane / 7, aj = lane - ai * 7;
        float a = adj[(size_t)batch * 49 + lane];
        if (ai == aj) a = 1.0f;
        fw[lane] = a;
    }
    WFENCE();
    float adjr = 0.0f;
    if (lane < 49) {
        int ai = lane / 7, aj = lane - ai * 7;
        float si = 0.f, sj = 0.f;
        #pragma unroll
        for (int m = 0; m < 7; ++m) { si += fw[ai * 7 + m]; sj += fw[aj * 7 + m]; }
        si = fmaxf(si, 1.0f); sj = fmaxf(sj, 1.0f);
        adjr = fw[lane] / (sqrtf(si) * sqrtf(sj));
    }
    WFENCE();
    // zero hx (rows 0-6, hi+lo)
    #pragma unroll
    for (int n = 0; n < 7; ++n) { aw[896 + n * 64 + lane] = 0; aw[1344 + n * 64 + lane] = 0; }
    WFENCE();
    __syncthreads();   // gate frags ready

    float cx[16];
    #pragma unroll
    for (int i = 0; i < 16; ++i) cx[i] = 0.0f;
    float xr0 = 0.f, xr1 = 0.f;

    const s8v* wsv = (const s8v*)ws;
    const s8v* gv  = (const s8v*)(sp + 16384);

    auto cell = [&]() {
        // ---- encoder (VALU fp32): e[m][lane=h] ----
        float e[7];
        #pragma unroll
        for (int n = 0; n < 7; ++n) e[n] = benc;
        #pragma unroll
        for (int f = 0; f < 11; ++f) {
            float w = encw[f * 64 + lane];
            #pragma unroll
            for (int n = 0; n < 7; ++n) {
                const int fl = n * 11 + f;
                float xv = (fl < 64) ? rdl(xr0, fl) : rdl(xr1, fl - 64);
                e[n] = fmaf(xv, w, e[n]);
            }
        }
        #pragma unroll
        for (int n = 0; n < 7; ++n) e[n] = fmaxf(e[n], 0.0f);
        // ---- mix1 on regs: ae = adj @ e ; split-store to Rs ----
        #pragma unroll
        for (int n = 0; n < 7; ++n) {
            float a = 0.f;
            #pragma unroll
            for (int m = 0; m < 7; ++m) a = fmaf(rdl(adjr, n * 7 + m), e[m], a);
            unsigned short h, l; hsplit(a, h, l);
            aw[n * 64 + lane] = h; aw[448 + n * 64 + lane] = l;
        }
        WFENCE();
        // ---- gcn1 MFMA: s1 = relu(ae @ W1 + b1); A=hi*hi, B=cross terms, s1=A+B/2048 ----
        {
            s8v ah0 = *(const s8v*)(aw + c15 * 64 + q * 8);
            s8v ah1 = *(const s8v*)(aw + c15 * 64 + 32 + q * 8);
            s8v al0 = *(const s8v*)(aw + 448 + c15 * 64 + q * 8);
            s8v al1 = *(const s8v*)(aw + 448 + c15 * 64 + 32 + q * 8);
            f4v res[4];
            #pragma unroll
            for (int nt = 0; nt < 4; ++nt) {
                f4v A = {bg1v[nt], bg1v[nt], bg1v[nt], bg1v[nt]};
                f4v Bk = {0.f, 0.f, 0.f, 0.f};
                int b0 = nt * 128 + lane;
                s8v wh0 = wsv[b0], wh1 = wsv[b0 + 64];
                s8v wl0 = wsv[512 + b0], wl1 = wsv[512 + b0 + 64];
                A  = mfmah(ah0, wh0, A);  A  = mfmah(ah1, wh1, A);
                Bk = mfmah(al0, wh0, Bk); Bk = mfmah(al1, wh1, Bk);
                Bk = mfmah(ah0, wl0, Bk); Bk = mfmah(ah1, wl1, Bk);
                res[nt] = A + Bk * INV2048;
            }
            #pragma unroll
            for (int nt = 0; nt < 4; ++nt) {
                #pragma unroll
                for (int r = 0; r < 4; ++r) {
                    int m = q * 4 + r;
                    float v = fmaxf(res[nt][r], 0.0f);
                    if (m < 7) {
                        unsigned short h, l; hsplit(v, h, l);
                        aw[m * 64 + nt * 16 + c15] = h; aw[448 + m * 64 + nt * 16 + c15] = l;
                    }
                }
            }
        }
        WFENCE();
        // ---- readback s1 per lane=h; mix2; store ae2 ----
        float s1[7];
        #pragma unroll
        for (int n = 0; n < 7; ++n) s1[n] = hjoin(aw[n * 64 + lane], aw[448 + n * 64 + lane]);
        #pragma unroll
        for (int n = 0; n < 7; ++n) {
            float a = 0.f;
            #pragma unroll
            for (int m = 0; m < 7; ++m) a = fmaf(rdl(adjr, n * 7 + m), s1[m], a);
            unsigned short h, l; hsplit(a, h, l);
            aw[n * 64 + lane] = h; aw[448 + n * 64 + lane] = l;
        }
        WFENCE();
        // ---- gcn2 MFMA: s2 = relu(ae2 @ W2 + b2) ----
        {
            s8v ah0 = *(const s8v*)(aw + c15 * 64 + q * 8);
            s8v ah1 = *(const s8v*)(aw + c15 * 64 + 32 + q * 8);
            s8v al0 = *(const s8v*)(aw + 448 + c15 * 64 + q * 8);
            s8v al1 = *(const s8v*)(aw + 448 + c15 * 64 + 32 + q * 8);
            f4v res[4];
            #pragma unroll
            for (int nt = 0; nt < 4; ++nt) {
                f4v A = {bg2v[nt], bg2v[nt], bg2v[nt], bg2v[nt]};
                f4v Bk = {0.f, 0.f, 0.f, 0.f};
                int b0 = nt * 128 + lane;
                s8v wh0 = wsv[1024 + b0], wh1 = wsv[1024 + b0 + 64];
                s8v wl0 = wsv[1536 + b0], wl1 = wsv[1536 + b0 + 64];
                A  = mfmah(ah0, wh0, A);  A  = mfmah(ah1, wh1, A);
                Bk = mfmah(al0, wh0, Bk); Bk = mfmah(al1, wh1, Bk);
                Bk = mfmah(ah0, wl0, Bk); Bk = mfmah(ah1, wl1, Bk);
                res[nt] = A + Bk * INV2048;
            }
            #pragma unroll
            for (int nt = 0; nt < 4; ++nt) {
                #pragma unroll
                for (int r = 0; r < 4; ++r) {
                    int m = q * 4 + r;
                    float v = fmaxf(res[nt][r], 0.0f);
                    if (m < 7) {
                        unsigned short h, l; hsplit(v, h, l);
                        aw[m * 64 + nt * 16 + c15] = h; aw[448 + m * 64 + nt * 16 + c15] = l;
                    }
                }
            }
        }
        WFENCE();
        // ---- gates MFMA: g = s2@wih^T + hx@whh^T + b ----
        s8v s2h0 = *(const s8v*)(aw + c15 * 64 + q * 8);
        s8v s2h1 = *(const s8v*)(aw + c15 * 64 + 32 + q * 8);
        s8v s2l0 = *(const s8v*)(aw + 448 + c15 * 64 + q * 8);
        s8v s2l1 = *(const s8v*)(aw + 448 + c15 * 64 + 32 + q * 8);
        s8v hxh0 = *(const s8v*)(aw + 896 + c15 * 64 + q * 8);
        s8v hxh1 = *(const s8v*)(aw + 896 + c15 * 64 + 32 + q * 8);
        s8v hxl0 = *(const s8v*)(aw + 1344 + c15 * 64 + q * 8);
        s8v hxl1 = *(const s8v*)(aw + 1344 + c15 * 64 + 32 + q * 8);
        f4v gacc[16];
        #pragma unroll
        for (int nt = 0; nt < 16; ++nt) {
            f4v A = {biasg[nt], biasg[nt], biasg[nt], biasg[nt]};
            f4v Bk = {0.f, 0.f, 0.f, 0.f};
            int b0 = nt * 128 + lane;
            s8v wih0 = gv[b0],        wih1 = gv[b0 + 64];
            s8v wil0 = gv[2048 + b0], wil1 = gv[2048 + b0 + 64];
            s8v whh0 = gv[4096 + b0], whh1 = gv[4096 + b0 + 64];
            s8v whl0 = gv[6144 + b0], whl1 = gv[6144 + b0 + 64];
            A  = mfmah(s2h0, wih0, A);  A  = mfmah(s2h1, wih1, A);
            A  = mfmah(hxh0, whh0, A);  A  = mfmah(hxh1, whh1, A);
            Bk = mfmah(s2l0, wih0, Bk); Bk = mfmah(s2l1, wih1, Bk);
            Bk = mfmah(s2h0, wil0, Bk); Bk = mfmah(s2h1, wil1, Bk);
            Bk = mfmah(hxl0, whh0, Bk); Bk = mfmah(hxl1, whh1, Bk);
            Bk = mfmah(hxh0, whl0, Bk); Bk = mfmah(hxh1, whl1, Bk);
            gacc[nt] = A + Bk * INV2048;
        }
        // ---- LSTM pointwise + hx split-store ----
        #pragma unroll
        for (int hb = 0; hb < 4; ++hb) {
            #pragma unroll
            for (int r = 0; r < 4; ++r) {
                float iv = fsigm(gacc[hb][r]);
                float fv = fsigm(gacc[4 + hb][r]);
                float gg = ftanh_(gacc[8 + hb][r]);
                float ov = fsigm(gacc[12 + hb][r]);
                float cc = fmaf(fv, cx[hb * 4 + r], iv * gg);
                cx[hb * 4 + r] = cc;
                float hh = ov * ftanh_(cc);
                int m = q * 4 + r;
                if (m < 7) {
                    unsigned short h, l; hsplit(hh, h, l);
                    aw[896 + m * 64 + hb * 16 + c15] = h;
                    aw[1344 + m * 64 + hb * 16 + c15] = l;
                }
            }
        }
        WFENCE();
    };

    // ---- history scan ----
    const float* xb = xh + (size_t)batch * 1848;  // 24*77
    #pragma unroll 1
    for (int t = 0; t < 24; ++t) {
        xr0 = xb[t * 77 + lane];
        xr1 = (lane < 13) ? xb[t * 77 + 64 + lane] : 0.0f;
        cell();
    }
    // init pred scratch from t=23 frame
    gapf[lane] = xr0;
    if (lane < 13) gapf[64 + lane] = xr1;
    WFENCE();

    // ---- autoregressive future scan ----
    float* outb = out + (size_t)batch * 2016;     // 48*42
    #pragma unroll 1
    for (int st = 0; st < 48; ++st) {
        cell();
        // dec1 MFMA: d1 = relu(hx @ dec_w1 + b1) -> fp32 stride-33 in own float view
        {
            s8v hxh0 = *(const s8v*)(aw + 896 + c15 * 64 + q * 8);
            s8v hxh1 = *(const s8v*)(aw + 896 + c15 * 64 + 32 + q * 8);
            s8v hxl0 = *(const s8v*)(aw + 1344 + c15 * 64 + q * 8);
            s8v hxl1 = *(const s8v*)(aw + 1344 + c15 * 64 + 32 + q * 8);
            #pragma unroll
            for (int nt = 0; nt < 2; ++nt) {
                f4v A = {bdec[nt], bdec[nt], bdec[nt], bdec[nt]};
                f4v Bk = {0.f, 0.f, 0.f, 0.f};
                int b0 = 2048 + nt * 128 + lane;
                s8v wh0 = wsv[b0], wh1 = wsv[b0 + 64];
                s8v wl0 = wsv[256 + b0], wl1 = wsv[256 + b0 + 64];
                A  = mfmah(hxh0, wh0, A);  A  = mfmah(hxh1, wh1, A);
                Bk = mfmah(hxl0, wh0, Bk); Bk = mfmah(hxl1, wh1, Bk);
                Bk = mfmah(hxh0, wl0, Bk); Bk = mfmah(hxh1, wl1, Bk);
                f4v res = A + Bk * INV2048;
                #pragma unroll
                for (int r = 0; r < 4; ++r) {
                    int m = q * 4 + r;
                    if (m < 7) fw[m * 33 + nt * 16 + c15] = fmaxf(res[r], 0.0f);
                }
            }
        }
        WFENCE();
        // dec2 + residual + clip + store
        if (lane < 42) {
            float a = bd2;
            #pragma unroll 8
            for (int jj = 0; jj < 32; ++jj)
                a = fmaf(fw[dn * 33 + jj], d2w[jj * 6 + dd], a);
            float p = gapf[dn * 11 + dd] + ftanh_(a) * 0.05f;
            p = fminf(fmaxf(p, 0.0f), 1.0f);
            gapf[dn * 11 + dd] = p;
            outb[st * 42 + lane] = p;
        }
        WFENCE();
        // update x regs from pred scratch (dyn features only)
        if (u0) xr0 = gapf[lane];
        if (u1) xr1 = gapf[64 + lane];
    }
}

extern "C" void kernel_launch(void* const* d_in, const int* in_sizes, int n_in,
                              void* d_out, int out_size, void* d_ws, size_t ws_size,
                              hipStream_t stream)
{
    const float* xh   = (const float*)d_in[0];
    const float* adjp = (const float*)d_in[1];
    const float* encw = (const float*)d_in[2];
    const float* encb = (const float*)d_in[3];
    const float* g1w  = (const float*)d_in[4];
    const float* g1b  = (const float*)d_in[5];
    const float* g2w  = (const float*)d_in[6];
    const float* g2b  = (const float*)d_in[7];
    const float* wih  = (const float*)d_in[8];
    const float* whh  = (const float*)d_in[9];
    const float* bih  = (const float*)d_in[10];
    const float* bhh  = (const float*)d_in[11];
    const float* d1w  = (const float*)d_in[12];
    const float* d1b  = (const float*)d_in[13];
    const float* d2w  = (const float*)d_in[14];
    const float* d2b  = (const float*)d_in[15];
    float* out = (float*)d_out;
    unsigned short* ws = (unsigned short*)d_ws;

    hipLaunchKernelGGL(build_ws, dim3(1), dim3(256), 0, stream, g1w, g2w, d1w, ws);
    hipLaunchKernelGGL(stgnn, dim3(512), dim3(512), 0, stream,
                       xh, adjp, encw, encb, g1b, g2b, wih, whh, bih, bhh,
                       d1b, d2w, d2b, (const unsigned short*)ws, out);
}

// Round 8
// 1999.107 us; speedup vs baseline: 1.8555x; 1.8555x over previous
//
#include <hip/hip_runtime.h>
#include <math.h>

typedef __attribute__((ext_vector_type(8))) short s8v;
typedef __attribute__((ext_vector_type(8))) _Float16 h8v;
typedef __attribute__((ext_vector_type(4))) float f4v;
typedef __attribute__((ext_vector_type(2))) int i2v;
typedef long long ll64;

#define L2E 1.44269504089f
#define INV2048 4.8828125e-4f
__device__ __forceinline__ float fexp2(float x) { return __builtin_amdgcn_exp2f(x); }
__device__ __forceinline__ float frcp(float x)  { return __builtin_amdgcn_rcpf(x); }
__device__ __forceinline__ float fsigm(float x) { return frcp(1.0f + fexp2(-L2E * x)); }
__device__ __forceinline__ float ftanh_(float x){ return 1.0f - 2.0f * frcp(fexp2((2.0f*L2E) * x) + 1.0f); }
__device__ __forceinline__ float rdl(float v, int l) {
    return __uint_as_float(__builtin_amdgcn_readlane(__float_as_uint(v), l));
}
#define WFENCE() asm volatile("s_waitcnt lgkmcnt(0)" ::: "memory")

// fp16 scaled split: x ~= hi + lo/2048, lo kept in normal fp16 range (flush-proof).
__device__ __forceinline__ void hsplit(float x, unsigned short& hi, unsigned short& lo) {
    _Float16 h = (_Float16)x;
    _Float16 l = (_Float16)((x - (float)h) * 2048.0f);
    hi = __builtin_bit_cast(unsigned short, h);
    lo = __builtin_bit_cast(unsigned short, l);
}
__device__ __forceinline__ float hjoin(unsigned short hi, unsigned short lo) {
    return (float)__builtin_bit_cast(_Float16, hi)
         + (float)__builtin_bit_cast(_Float16, lo) * INV2048;
}
__device__ __forceinline__ f4v mfmah(s8v a, s8v b, f4v c) {
    return __builtin_amdgcn_mfma_f32_16x16x32_f16(
        __builtin_bit_cast(h8v, a), __builtin_bit_cast(h8v, b), c, 0, 0, 0);
}
__device__ __forceinline__ f4v mfma8(ll64 a, ll64 b, f4v c) {
    return __builtin_amdgcn_mfma_f32_16x16x32_fp8_fp8(a, b, c, 0, 0, 0);
}
// fp16x8 fragment -> fp8(e4m3)x8 operand (same k ordering: byte j = elem j)
__device__ __forceinline__ ll64 pk8(s8v hf) {
    h8v h = __builtin_bit_cast(h8v, hf);
    int lo = __builtin_amdgcn_cvt_pk_fp8_f32((float)h[0], (float)h[1], 0, false);
    lo = __builtin_amdgcn_cvt_pk_fp8_f32((float)h[2], (float)h[3], lo, true);
    int hi = __builtin_amdgcn_cvt_pk_fp8_f32((float)h[4], (float)h[5], 0, false);
    hi = __builtin_amdgcn_cvt_pk_fp8_f32((float)h[6], (float)h[7], hi, true);
    i2v r; r[0] = lo; r[1] = hi;
    return __builtin_bit_cast(ll64, r);
}
__device__ __forceinline__ unsigned char fp8b(float x) {
    return (unsigned char)(__builtin_amdgcn_cvt_pk_fp8_f32(x, 0.0f, 0, false) & 0xff);
}

// ---------------- d_ws / LDS shared layout (bytes) ----------------
// GHI  [0,      65536): gates hi fp16, frag f = nt*4+mat*2+kh (64 frags x 1024 B)
// GLO  [65536,  98304): gates lo fp8  (64 frags x 512 B)
// CHI  [98304, 114688): gcn hi fp16,  frag f = g*8+nt*2+kh (16 x 1024)
// CLO  [114688,122880): gcn lo fp8    (16 x 512)
// DHI  [122880,126976): dec hi fp16,  frag f = nt*2+kh (4 x 1024)
// LDS only:
// ENCW [126976,129792): enc_w fp32 (704 floats)
// D2W  [129792,130560): dec_w2 fp32 (192 floats)
// ACTS [130560,159232): per-wave 3584 B: RsHi RsLo RhHi RhLo (448 shorts each)
// GAPF [159232,161792): per-wave 80 floats pred scratch
#define OFF_GLO  65536
#define OFF_CHI  98304
#define OFF_CLO  114688
#define OFF_DHI  122880
#define OFF_ENCW 126976
#define OFF_D2W  129792
#define OFF_ACTS 130560
#define OFF_GAPF 159232

// ---------- prologue: build ALL weight fragments into d_ws ----------
__global__ __launch_bounds__(256) void build_ws(
    const float* __restrict__ g1w, const float* __restrict__ g2w,
    const float* __restrict__ d1w, const float* __restrict__ wih,
    const float* __restrict__ whh, unsigned char* __restrict__ ws)
{
    const int tid = threadIdx.x;  // 256
    unsigned short* GHI = (unsigned short*)ws;
    unsigned char*  GLO = ws + OFF_GLO;
    unsigned short* CHI = (unsigned short*)(ws + OFF_CHI);
    unsigned char*  CLO = ws + OFF_CLO;
    unsigned short* DHI = (unsigned short*)(ws + OFF_DHI);

    // gates: B[k][c] = wih/whh[c*64+k]
    for (int u = tid; u < 4096; u += 256) {
        int f = u >> 6, ln = u & 63;
        int nt = f >> 2, mat = (f >> 1) & 1, kh = f & 1;
        int col = nt * 16 + (ln & 15);
        int k0 = kh * 32 + ((ln >> 4) & 3) * 8;
        const float* W = mat ? whh : wih;
        #pragma unroll
        for (int j = 0; j < 8; ++j) {
            float w = W[col * 64 + k0 + j];
            _Float16 h = (_Float16)w;
            float r = (w - (float)h) * 2048.0f;
            GHI[f * 512 + ln * 8 + j] = __builtin_bit_cast(unsigned short, h);
            GLO[f * 512 + ln * 8 + j] = fp8b(r);
        }
    }
    // gcn: B[k][n] = W[k*64+n]
    for (int u = tid; u < 1024; u += 256) {
        int f = u >> 6, ln = u & 63;
        int g = f >> 3, nt = (f >> 1) & 3, kh = f & 1;
        int n = nt * 16 + (ln & 15);
        int k0 = kh * 32 + ((ln >> 4) & 3) * 8;
        const float* W = g ? g2w : g1w;
        #pragma unroll
        for (int j = 0; j < 8; ++j) {
            float w = W[(k0 + j) * 64 + n];
            _Float16 h = (_Float16)w;
            float r = (w - (float)h) * 2048.0f;
            CHI[f * 512 + ln * 8 + j] = __builtin_bit_cast(unsigned short, h);
            CLO[f * 512 + ln * 8 + j] = fp8b(r);
        }
    }
    // dec: B[k][j] = d1w[k*32+j], hi only
    for (int u = tid; u < 256; u += 256) {
        int f = u >> 6, ln = u & 63;
        int nt = f >> 1, kh = f & 1;
        int n = nt * 16 + (ln & 15);
        int k0 = kh * 32 + ((ln >> 4) & 3) * 8;
        #pragma unroll
        for (int j = 0; j < 8; ++j) {
            _Float16 h = (_Float16)d1w[(k0 + j) * 32 + n];
            DHI[f * 512 + ln * 8 + j] = __builtin_bit_cast(unsigned short, h);
        }
    }
}

// ---------- main kernel: one wave = one batch, all weights LDS-resident ----------
__global__ __launch_bounds__(512, 2)
void stgnn(const float* __restrict__ xh,   const float* __restrict__ adj,
           const float* __restrict__ encw, const float* __restrict__ encb,
           const float* __restrict__ g1b,  const float* __restrict__ g2b,
           const float* __restrict__ bih,  const float* __restrict__ bhh,
           const float* __restrict__ d1b,  const float* __restrict__ d2w,
           const float* __restrict__ d2b,  const unsigned char* __restrict__ ws,
           float* __restrict__ out)
{
    __shared__ __align__(16) unsigned char pool[161792];

    const int tid  = threadIdx.x;
    const int lane = tid & 63;
    const int wv   = tid >> 6;
    const int q    = lane >> 4;
    const int c15  = lane & 15;
    const int batch = blockIdx.x * 8 + wv;

    // ---- one-time: copy prebuilt fragments d_ws -> LDS; stage encw/d2w ----
    {
        s8v* dst = (s8v*)pool;
        const s8v* src = (const s8v*)ws;
        for (int i = tid; i < 7936; i += 512) dst[i] = src[i];      // 126976 B
        float* pe = (float*)(pool + OFF_ENCW);
        for (int i = tid; i < 704; i += 512) pe[i] = encw[i];
        float* pd = (float*)(pool + OFF_D2W);
        if (tid < 192) pd[tid] = d2w[tid];
    }

    unsigned short* aw = (unsigned short*)(pool + OFF_ACTS) + wv * 1792;
    float* fw = (float*)aw;                              // float view of own act region
    float* gapf = (float*)(pool + OFF_GAPF) + wv * 80;
    const s8v* GHIv = (const s8v*)pool;
    const unsigned char* GLO = pool + OFF_GLO;
    const s8v* CHIv = (const s8v*)(pool + OFF_CHI);
    const unsigned char* CLO = pool + OFF_CLO;
    const s8v* DHIv = (const s8v*)(pool + OFF_DHI);
    const float* encwL = (const float*)(pool + OFF_ENCW);
    const float* d2wL  = (const float*)(pool + OFF_D2W);

    // ---- biases ----
    float benc = encb[lane];
    float bg1v[4], bg2v[4], bdec[2], biasg[16];
    #pragma unroll
    for (int i = 0; i < 4; ++i) { bg1v[i] = g1b[i * 16 + c15]; bg2v[i] = g2b[i * 16 + c15]; }
    #pragma unroll
    for (int i = 0; i < 2; ++i) bdec[i] = d1b[i * 16 + c15];
    #pragma unroll
    for (int i = 0; i < 16; ++i) biasg[i] = bih[i * 16 + c15] + bhh[i * 16 + c15];
    const int dn = lane / 6, dd = lane - dn * 6;          // dec2 mapping (lane<42)
    float bd2 = d2b[lane < 42 ? dd : 0];
    const int lf0 = lane - (lane / 11) * 11;
    const bool u0 = lf0 < 6;
    const bool u1 = (lane >= 2) && (lane < 8);

    // ---- adjacency normalize (wave-local, own-region float scratch) ----
    if (lane < 49) {
        int ai = lane / 7, aj = lane - ai * 7;
        float a = adj[(size_t)batch * 49 + lane];
        if (ai == aj) a = 1.0f;
        fw[lane] = a;
    }
    WFENCE();
    float adjr = 0.0f;
    if (lane < 49) {
        int ai = lane / 7, aj = lane - ai * 7;
        float si = 0.f, sj = 0.f;
        #pragma unroll
        for (int m = 0; m < 7; ++m) { si += fw[ai * 7 + m]; sj += fw[aj * 7 + m]; }
        si = fmaxf(si, 1.0f); sj = fmaxf(sj, 1.0f);
        adjr = fw[lane] / (sqrtf(si) * sqrtf(sj));
    }
    WFENCE();
    // zero hx (rows 0-6, hi+lo)
    #pragma unroll
    for (int n = 0; n < 7; ++n) { aw[896 + n * 64 + lane] = 0; aw[1344 + n * 64 + lane] = 0; }
    WFENCE();
    __syncthreads();   // fragments + encw/d2w staged

    float cx[16];
    #pragma unroll
    for (int i = 0; i < 16; ++i) cx[i] = 0.0f;
    float xr0 = 0.f, xr1 = 0.f;

    auto cell = [&]() {
        // ---- encoder (VALU fp32, weights from LDS) ----
        float e[7];
        #pragma unroll
        for (int n = 0; n < 7; ++n) e[n] = benc;
        #pragma unroll
        for (int f = 0; f < 11; ++f) {
            float w = encwL[f * 64 + lane];
            #pragma unroll
            for (int n = 0; n < 7; ++n) {
                const int fl = n * 11 + f;
                float xv = (fl < 64) ? rdl(xr0, fl) : rdl(xr1, fl - 64);
                e[n] = fmaf(xv, w, e[n]);
            }
        }
        #pragma unroll
        for (int n = 0; n < 7; ++n) e[n] = fmaxf(e[n], 0.0f);
        // ---- mix1: ae = adj @ e ; split-store to Rs ----
        #pragma unroll
        for (int n = 0; n < 7; ++n) {
            float a = 0.f;
            #pragma unroll
            for (int m = 0; m < 7; ++m) a = fmaf(rdl(adjr, n * 7 + m), e[m], a);
            unsigned short h, l; hsplit(a, h, l);
            aw[n * 64 + lane] = h; aw[448 + n * 64 + lane] = l;
        }
        WFENCE();
        // ---- gcn1 MFMA ----
        {
            s8v ah0 = *(const s8v*)(aw + c15 * 64 + q * 8);
            s8v ah1 = *(const s8v*)(aw + c15 * 64 + 32 + q * 8);
            s8v al0 = *(const s8v*)(aw + 448 + c15 * 64 + q * 8);
            s8v al1 = *(const s8v*)(aw + 448 + c15 * 64 + 32 + q * 8);
            ll64 a80 = pk8(ah0), a81 = pk8(ah1);
            f4v res[4];
            #pragma unroll
            for (int nt = 0; nt < 4; ++nt) {
                s8v wh0 = CHIv[(nt * 2 + 0) * 64 + lane];
                s8v wh1 = CHIv[(nt * 2 + 1) * 64 + lane];
                ll64 wl0 = *(const ll64*)(CLO + (nt * 2 + 0) * 512 + lane * 8);
                ll64 wl1 = *(const ll64*)(CLO + (nt * 2 + 1) * 512 + lane * 8);
                f4v A = {bg1v[nt], bg1v[nt], bg1v[nt], bg1v[nt]};
                f4v B = {0.f, 0.f, 0.f, 0.f};
                A = mfmah(ah0, wh0, A); A = mfmah(ah1, wh1, A);
                B = mfmah(al0, wh0, B); B = mfmah(al1, wh1, B);
                B = mfma8(a80, wl0, B); B = mfma8(a81, wl1, B);
                res[nt] = A + B * INV2048;
            }
            #pragma unroll
            for (int nt = 0; nt < 4; ++nt) {
                #pragma unroll
                for (int r = 0; r < 4; ++r) {
                    int m = q * 4 + r;
                    float v = fmaxf(res[nt][r], 0.0f);
                    if (m < 7) {
                        unsigned short h, l; hsplit(v, h, l);
                        aw[m * 64 + nt * 16 + c15] = h; aw[448 + m * 64 + nt * 16 + c15] = l;
                    }
                }
            }
        }
        WFENCE();
        // ---- readback s1; mix2; store ae2 ----
        float s1[7];
        #pragma unroll
        for (int n = 0; n < 7; ++n) s1[n] = hjoin(aw[n * 64 + lane], aw[448 + n * 64 + lane]);
        #pragma unroll
        for (int n = 0; n < 7; ++n) {
            float a = 0.f;
            #pragma unroll
            for (int m = 0; m < 7; ++m) a = fmaf(rdl(adjr, n * 7 + m), s1[m], a);
            unsigned short h, l; hsplit(a, h, l);
            aw[n * 64 + lane] = h; aw[448 + n * 64 + lane] = l;
        }
        WFENCE();
        // ---- gcn2 MFMA ----
        {
            s8v ah0 = *(const s8v*)(aw + c15 * 64 + q * 8);
            s8v ah1 = *(const s8v*)(aw + c15 * 64 + 32 + q * 8);
            s8v al0 = *(const s8v*)(aw + 448 + c15 * 64 + q * 8);
            s8v al1 = *(const s8v*)(aw + 448 + c15 * 64 + 32 + q * 8);
            ll64 a80 = pk8(ah0), a81 = pk8(ah1);
            f4v res[4];
            #pragma unroll
            for (int nt = 0; nt < 4; ++nt) {
                s8v wh0 = CHIv[(8 + nt * 2 + 0) * 64 + lane];
                s8v wh1 = CHIv[(8 + nt * 2 + 1) * 64 + lane];
                ll64 wl0 = *(const ll64*)(CLO + (8 + nt * 2 + 0) * 512 + lane * 8);
                ll64 wl1 = *(const ll64*)(CLO + (8 + nt * 2 + 1) * 512 + lane * 8);
                f4v A = {bg2v[nt], bg2v[nt], bg2v[nt], bg2v[nt]};
                f4v B = {0.f, 0.f, 0.f, 0.f};
                A = mfmah(ah0, wh0, A); A = mfmah(ah1, wh1, A);
                B = mfmah(al0, wh0, B); B = mfmah(al1, wh1, B);
                B = mfma8(a80, wl0, B); B = mfma8(a81, wl1, B);
                res[nt] = A + B * INV2048;
            }
            #pragma unroll
            for (int nt = 0; nt < 4; ++nt) {
                #pragma unroll
                for (int r = 0; r < 4; ++r) {
                    int m = q * 4 + r;
                    float v = fmaxf(res[nt][r], 0.0f);
                    if (m < 7) {
                        unsigned short h, l; hsplit(v, h, l);
                        aw[m * 64 + nt * 16 + c15] = h; aw[448 + m * 64 + nt * 16 + c15] = l;
                    }
                }
            }
        }
        WFENCE();
        // ---- gates MFMA: g = s2@wih^T + hx@whh^T + b ----
        s8v s2h0 = *(const s8v*)(aw + c15 * 64 + q * 8);
        s8v s2h1 = *(const s8v*)(aw + c15 * 64 + 32 + q * 8);
        s8v s2l0 = *(const s8v*)(aw + 448 + c15 * 64 + q * 8);
        s8v s2l1 = *(const s8v*)(aw + 448 + c15 * 64 + 32 + q * 8);
        s8v hxh0 = *(const s8v*)(aw + 896 + c15 * 64 + q * 8);
        s8v hxh1 = *(const s8v*)(aw + 896 + c15 * 64 + 32 + q * 8);
        s8v hxl0 = *(const s8v*)(aw + 1344 + c15 * 64 + q * 8);
        s8v hxl1 = *(const s8v*)(aw + 1344 + c15 * 64 + 32 + q * 8);
        ll64 s280 = pk8(s2h0), s281 = pk8(s2h1);
        ll64 hx80 = pk8(hxh0), hx81 = pk8(hxh1);
        f4v gacc[16];
        #pragma unroll 4
        for (int nt = 0; nt < 16; ++nt) {
            int fb = nt * 4;
            s8v wi0 = GHIv[(fb + 0) * 64 + lane];
            s8v wi1 = GHIv[(fb + 1) * 64 + lane];
            s8v wh0 = GHIv[(fb + 2) * 64 + lane];
            s8v wh1 = GHIv[(fb + 3) * 64 + lane];
            ll64 li0 = *(const ll64*)(GLO + (fb + 0) * 512 + lane * 8);
            ll64 li1 = *(const ll64*)(GLO + (fb + 1) * 512 + lane * 8);
            ll64 lh0 = *(const ll64*)(GLO + (fb + 2) * 512 + lane * 8);
            ll64 lh1 = *(const ll64*)(GLO + (fb + 3) * 512 + lane * 8);
            f4v A = {biasg[nt], biasg[nt], biasg[nt], biasg[nt]};
            f4v B = {0.f, 0.f, 0.f, 0.f};
            A = mfmah(s2h0, wi0, A); A = mfmah(s2h1, wi1, A);
            A = mfmah(hxh0, wh0, A); A = mfmah(hxh1, wh1, A);
            B = mfmah(s2l0, wi0, B); B = mfmah(s2l1, wi1, B);
            B = mfmah(hxl0, wh0, B); B = mfmah(hxl1, wh1, B);
            B = mfma8(s280, li0, B); B = mfma8(s281, li1, B);
            B = mfma8(hx80, lh0, B); B = mfma8(hx81, lh1, B);
            gacc[nt] = A + B * INV2048;
        }
        // ---- LSTM pointwise + hx split-store ----
        #pragma unroll
        for (int hb = 0; hb < 4; ++hb) {
            #pragma unroll
            for (int r = 0; r < 4; ++r) {
                float iv = fsigm(gacc[hb][r]);
                float fv = fsigm(gacc[4 + hb][r]);
                float gg = ftanh_(gacc[8 + hb][r]);
                float ov = fsigm(gacc[12 + hb][r]);
                float cc = fmaf(fv, cx[hb * 4 + r], iv * gg);
                cx[hb * 4 + r] = cc;
                float hh = ov * ftanh_(cc);
                int m = q * 4 + r;
                if (m < 7) {
                    unsigned short h, l; hsplit(hh, h, l);
                    aw[896 + m * 64 + hb * 16 + c15] = h;
                    aw[1344 + m * 64 + hb * 16 + c15] = l;
                }
            }
        }
        WFENCE();
    };

    // ---- history scan ----
    const float* xb = xh + (size_t)batch * 1848;
    #pragma unroll 1
    for (int t = 0; t < 24; ++t) {
        xr0 = xb[t * 77 + lane];
        xr1 = (lane < 13) ? xb[t * 77 + 64 + lane] : 0.0f;
        cell();
    }
    gapf[lane] = xr0;
    if (lane < 13) gapf[64 + lane] = xr1;
    WFENCE();

    // ---- autoregressive future scan ----
    float* outb = out + (size_t)batch * 2016;
    #pragma unroll 1
    for (int st = 0; st < 48; ++st) {
        cell();
        // dec1 MFMA (hi + act-lo cross): d1 -> fp32 stride-33 in own float view
        {
            s8v hxh0 = *(const s8v*)(aw + 896 + c15 * 64 + q * 8);
            s8v hxh1 = *(const s8v*)(aw + 896 + c15 * 64 + 32 + q * 8);
            s8v hxl0 = *(const s8v*)(aw + 1344 + c15 * 64 + q * 8);
            s8v hxl1 = *(const s8v*)(aw + 1344 + c15 * 64 + 32 + q * 8);
            #pragma unroll
            for (int nt = 0; nt < 2; ++nt) {
                s8v wh0 = DHIv[(nt * 2 + 0) * 64 + lane];
                s8v wh1 = DHIv[(nt * 2 + 1) * 64 + lane];
                f4v A = {bdec[nt], bdec[nt], bdec[nt], bdec[nt]};
                f4v B = {0.f, 0.f, 0.f, 0.f};
                A = mfmah(hxh0, wh0, A); A = mfmah(hxh1, wh1, A);
                B = mfmah(hxl0, wh0, B); B = mfmah(hxl1, wh1, B);
                f4v res = A + B * INV2048;
                #pragma unroll
                for (int r = 0; r < 4; ++r) {
                    int m = q * 4 + r;
                    if (m < 7) fw[m * 33 + nt * 16 + c15] = fmaxf(res[r], 0.0f);
                }
            }
        }
        WFENCE();
        // dec2 + residual + clip + store
        if (lane < 42) {
            float a = bd2;
            #pragma unroll 8
            for (int jj = 0; jj < 32; ++jj)
                a = fmaf(fw[dn * 33 + jj], d2wL[jj * 6 + dd], a);
            float p = gapf[dn * 11 + dd] + ftanh_(a) * 0.05f;
            p = fminf(fmaxf(p, 0.0f), 1.0f);
            gapf[dn * 11 + dd] = p;
            outb[st * 42 + lane] = p;
        }
        WFENCE();
        if (u0) xr0 = gapf[lane];
        if (u1) xr1 = gapf[64 + lane];
    }
}

extern "C" void kernel_launch(void* const* d_in, const int* in_sizes, int n_in,
                              void* d_out, int out_size, void* d_ws, size_t ws_size,
                              hipStream_t stream)
{
    const float* xh   = (const float*)d_in[0];
    const float* adjp = (const float*)d_in[1];
    const float* encw = (const float*)d_in[2];
    const float* encb = (const float*)d_in[3];
    const float* g1w  = (const float*)d_in[4];
    const float* g1b  = (const float*)d_in[5];
    const float* g2w  = (const float*)d_in[6];
    const float* g2b  = (const float*)d_in[7];
    const float* wih  = (const float*)d_in[8];
    const float* whh  = (const float*)d_in[9];
    const float* bih  = (const float*)d_in[10];
    const float* bhh  = (const float*)d_in[11];
    const float* d1w  = (const float*)d_in[12];
    const float* d1b  = (const float*)d_in[13];
    const float* d2w  = (const float*)d_in[14];
    const float* d2b  = (const float*)d_in[15];
    float* out = (float*)d_out;
    unsigned char* ws = (unsigned char*)d_ws;

    hipLaunchKernelGGL(build_ws, dim3(1), dim3(256), 0, stream, g1w, g2w, d1w, wih, whh, ws);
    hipLaunchKernelGGL(stgnn, dim3(512), dim3(512), 0, stream,
                       xh, adjp, encw, encb, g1b, g2b, bih, bhh,
                       d1b, d2w, d2b, (const unsigned char*)ws, out);
}

// Round 9
// 1587.193 us; speedup vs baseline: 2.3371x; 1.2595x over previous
//
#include <hip/hip_runtime.h>
#include <math.h>

typedef __attribute__((ext_vector_type(8))) short s8v;
typedef __attribute__((ext_vector_type(8))) _Float16 h8v;
typedef __attribute__((ext_vector_type(4))) float f4v;
typedef __attribute__((ext_vector_type(2))) int i2v;
typedef long long ll64;

#define L2E 1.44269504089f
#define INV2048 4.8828125e-4f
__device__ __forceinline__ float fexp2(float x) { return __builtin_amdgcn_exp2f(x); }
__device__ __forceinline__ float frcp(float x)  { return __builtin_amdgcn_rcpf(x); }
__device__ __forceinline__ float fsigm(float x) { return frcp(1.0f + fexp2(-L2E * x)); }
__device__ __forceinline__ float ftanh_(float x){ return 1.0f - 2.0f * frcp(fexp2((2.0f*L2E) * x) + 1.0f); }
__device__ __forceinline__ float rdl(float v, int l) {
    return __uint_as_float(__builtin_amdgcn_readlane(__float_as_uint(v), l));
}
#define WFENCE() asm volatile("s_waitcnt lgkmcnt(0)" ::: "memory")

// fp16 scaled split: x ~= hi + lo/2048, lo kept in normal fp16 range (flush-proof).
__device__ __forceinline__ void hsplit(float x, unsigned short& hi, unsigned short& lo) {
    _Float16 h = (_Float16)x;
    _Float16 l = (_Float16)((x - (float)h) * 2048.0f);
    hi = __builtin_bit_cast(unsigned short, h);
    lo = __builtin_bit_cast(unsigned short, l);
}
__device__ __forceinline__ float hjoin(unsigned short hi, unsigned short lo) {
    return (float)__builtin_bit_cast(_Float16, hi)
         + (float)__builtin_bit_cast(_Float16, lo) * INV2048;
}
__device__ __forceinline__ f4v mfmah(s8v a, s8v b, f4v c) {
    return __builtin_amdgcn_mfma_f32_16x16x32_f16(
        __builtin_bit_cast(h8v, a), __builtin_bit_cast(h8v, b), c, 0, 0, 0);
}
__device__ __forceinline__ f4v mfma8(ll64 a, ll64 b, f4v c) {
    return __builtin_amdgcn_mfma_f32_16x16x32_fp8_fp8(a, b, c, 0, 0, 0);
}
// fp16x8 fragment -> fp8(e4m3)x8 operand (same k ordering: byte j = elem j)
__device__ __forceinline__ ll64 pk8(s8v hf) {
    h8v h = __builtin_bit_cast(h8v, hf);
    int lo = __builtin_amdgcn_cvt_pk_fp8_f32((float)h[0], (float)h[1], 0, false);
    lo = __builtin_amdgcn_cvt_pk_fp8_f32((float)h[2], (float)h[3], lo, true);
    int hi = __builtin_amdgcn_cvt_pk_fp8_f32((float)h[4], (float)h[5], 0, false);
    hi = __builtin_amdgcn_cvt_pk_fp8_f32((float)h[6], (float)h[7], hi, true);
    i2v r; r[0] = lo; r[1] = hi;
    return __builtin_bit_cast(ll64, r);
}
__device__ __forceinline__ unsigned char fp8b(float x) {
    return (unsigned char)(__builtin_amdgcn_cvt_pk_fp8_f32(x, 0.0f, 0, false) & 0xff);
}

// ---------------- d_ws / LDS shared layout (bytes) ----------------
// GHI  [0,      65536): gates hi fp16, frag f = nt*4+mat*2+kh (64 frags x 1024 B)
// GLO  [65536,  98304): gates lo fp8  (64 frags x 512 B)
// CHI  [98304, 114688): gcn hi fp16,  frag f = g*8+nt*2+kh (16 x 1024)
// CLO  [114688,122880): gcn lo fp8    (16 x 512)
// DHI  [122880,126976): dec hi fp16,  frag f = nt*2+kh (4 x 1024)
// LDS only:
// ENCW [126976,129792): enc_w fp32 (704 floats)
// D2W  [129792,130560): dec_w2 fp32 (192 floats)
// ACTS [130560,159232): per-wave 3584 B: RsHi RsLo RhHi RhLo (448 shorts each)
// GAPF [159232,161792): per-wave 80 floats pred scratch
#define OFF_GLO  65536
#define OFF_CHI  98304
#define OFF_CLO  114688
#define OFF_DHI  122880
#define OFF_ENCW 126976
#define OFF_D2W  129792
#define OFF_ACTS 130560
#define OFF_GAPF 159232

// ---------- prologue: build ALL weight fragments into d_ws ----------
__global__ __launch_bounds__(256) void build_ws(
    const float* __restrict__ g1w, const float* __restrict__ g2w,
    const float* __restrict__ d1w, const float* __restrict__ wih,
    const float* __restrict__ whh, unsigned char* __restrict__ ws)
{
    const int tid = threadIdx.x;  // 256
    unsigned short* GHI = (unsigned short*)ws;
    unsigned char*  GLO = ws + OFF_GLO;
    unsigned short* CHI = (unsigned short*)(ws + OFF_CHI);
    unsigned char*  CLO = ws + OFF_CLO;
    unsigned short* DHI = (unsigned short*)(ws + OFF_DHI);

    // gates: B[k][c] = wih/whh[c*64+k]
    for (int u = tid; u < 4096; u += 256) {
        int f = u >> 6, ln = u & 63;
        int nt = f >> 2, mat = (f >> 1) & 1, kh = f & 1;
        int col = nt * 16 + (ln & 15);
        int k0 = kh * 32 + ((ln >> 4) & 3) * 8;
        const float* W = mat ? whh : wih;
        #pragma unroll
        for (int j = 0; j < 8; ++j) {
            float w = W[col * 64 + k0 + j];
            _Float16 h = (_Float16)w;
            float r = (w - (float)h) * 2048.0f;
            GHI[f * 512 + ln * 8 + j] = __builtin_bit_cast(unsigned short, h);
            GLO[f * 512 + ln * 8 + j] = fp8b(r);
        }
    }
    // gcn: B[k][n] = W[k*64+n]
    for (int u = tid; u < 1024; u += 256) {
        int f = u >> 6, ln = u & 63;
        int g = f >> 3, nt = (f >> 1) & 3, kh = f & 1;
        int n = nt * 16 + (ln & 15);
        int k0 = kh * 32 + ((ln >> 4) & 3) * 8;
        const float* W = g ? g2w : g1w;
        #pragma unroll
        for (int j = 0; j < 8; ++j) {
            float w = W[(k0 + j) * 64 + n];
            _Float16 h = (_Float16)w;
            float r = (w - (float)h) * 2048.0f;
            CHI[f * 512 + ln * 8 + j] = __builtin_bit_cast(unsigned short, h);
            CLO[f * 512 + ln * 8 + j] = fp8b(r);
        }
    }
    // dec: B[k][j] = d1w[k*32+j], hi only
    for (int u = tid; u < 256; u += 256) {
        int f = u >> 6, ln = u & 63;
        int nt = f >> 1, kh = f & 1;
        int n = nt * 16 + (ln & 15);
        int k0 = kh * 32 + ((ln >> 4) & 3) * 8;
        #pragma unroll
        for (int j = 0; j < 8; ++j) {
            _Float16 h = (_Float16)d1w[(k0 + j) * 32 + n];
            DHI[f * 512 + ln * 8 + j] = __builtin_bit_cast(unsigned short, h);
        }
    }
}

// ---------- main kernel: one wave = one batch, all weights LDS-resident ----------
__global__ __launch_bounds__(512, 2)
void stgnn(const float* __restrict__ xh,   const float* __restrict__ adj,
           const float* __restrict__ encw, const float* __restrict__ encb,
           const float* __restrict__ g1b,  const float* __restrict__ g2b,
           const float* __restrict__ bih,  const float* __restrict__ bhh,
           const float* __restrict__ d1b,  const float* __restrict__ d2w,
           const float* __restrict__ d2b,  const unsigned char* __restrict__ ws,
           float* __restrict__ out)
{
    __shared__ __align__(16) unsigned char pool[161792];

    const int tid  = threadIdx.x;
    const int lane = tid & 63;
    const int wv   = tid >> 6;
    const int q    = lane >> 4;
    const int c15  = lane & 15;
    const int batch = blockIdx.x * 8 + wv;

    // ---- one-time: copy prebuilt fragments d_ws -> LDS; stage encw/d2w ----
    {
        s8v* dst = (s8v*)pool;
        const s8v* src = (const s8v*)ws;
        for (int i = tid; i < 7936; i += 512) dst[i] = src[i];      // 126976 B
        float* pe = (float*)(pool + OFF_ENCW);
        for (int i = tid; i < 704; i += 512) pe[i] = encw[i];
        float* pd = (float*)(pool + OFF_D2W);
        if (tid < 192) pd[tid] = d2w[tid];
    }

    unsigned short* aw = (unsigned short*)(pool + OFF_ACTS) + wv * 1792;
    float* fw = (float*)aw;                              // float view of own act region
    float* gapf = (float*)(pool + OFF_GAPF) + wv * 80;
    const s8v* GHIv = (const s8v*)pool;
    const unsigned char* GLO = pool + OFF_GLO;
    const s8v* CHIv = (const s8v*)(pool + OFF_CHI);
    const unsigned char* CLO = pool + OFF_CLO;
    const s8v* DHIv = (const s8v*)(pool + OFF_DHI);
    const float* encwL = (const float*)(pool + OFF_ENCW);
    const float* d2wL  = (const float*)(pool + OFF_D2W);

    // ---- biases ----
    float benc = encb[lane];
    float bg1v[4], bg2v[4], bdec[2], biasg[16];
    #pragma unroll
    for (int i = 0; i < 4; ++i) { bg1v[i] = g1b[i * 16 + c15]; bg2v[i] = g2b[i * 16 + c15]; }
    #pragma unroll
    for (int i = 0; i < 2; ++i) bdec[i] = d1b[i * 16 + c15];
    #pragma unroll
    for (int i = 0; i < 16; ++i) biasg[i] = bih[i * 16 + c15] + bhh[i * 16 + c15];
    const int dn = lane / 6, dd = lane - dn * 6;          // dec2 mapping (lane<42)
    float bd2 = d2b[lane < 42 ? dd : 0];
    const int lf0 = lane - (lane / 11) * 11;
    const bool u0 = lf0 < 6;
    const bool u1 = (lane >= 2) && (lane < 8);

    // ---- adjacency normalize (wave-local, own-region float scratch) ----
    if (lane < 49) {
        int ai = lane / 7, aj = lane - ai * 7;
        float a = adj[(size_t)batch * 49 + lane];
        if (ai == aj) a = 1.0f;
        fw[lane] = a;
    }
    WFENCE();
    float adjr = 0.0f;
    if (lane < 49) {
        int ai = lane / 7, aj = lane - ai * 7;
        float si = 0.f, sj = 0.f;
        #pragma unroll
        for (int m = 0; m < 7; ++m) { si += fw[ai * 7 + m]; sj += fw[aj * 7 + m]; }
        si = fmaxf(si, 1.0f); sj = fmaxf(sj, 1.0f);
        adjr = fw[lane] / (sqrtf(si) * sqrtf(sj));
    }
    WFENCE();
    // zero hx (rows 0-6, hi+lo)
    #pragma unroll
    for (int n = 0; n < 7; ++n) { aw[896 + n * 64 + lane] = 0; aw[1344 + n * 64 + lane] = 0; }
    WFENCE();
    __syncthreads();   // fragments + encw/d2w staged

    float cx[16];
    #pragma unroll
    for (int i = 0; i < 16; ++i) cx[i] = 0.0f;
    float xr0 = 0.f, xr1 = 0.f;

    auto cell = [&]() {
        // ---- encoder (VALU fp32, weights from LDS) ----
        float e[7];
        #pragma unroll
        for (int n = 0; n < 7; ++n) e[n] = benc;
        #pragma unroll
        for (int f = 0; f < 11; ++f) {
            float w = encwL[f * 64 + lane];
            #pragma unroll
            for (int n = 0; n < 7; ++n) {
                const int fl = n * 11 + f;
                float xv = (fl < 64) ? rdl(xr0, fl) : rdl(xr1, fl - 64);
                e[n] = fmaf(xv, w, e[n]);
            }
        }
        #pragma unroll
        for (int n = 0; n < 7; ++n) e[n] = fmaxf(e[n], 0.0f);
        // ---- mix1: ae = adj @ e ; split-store to Rs ----
        #pragma unroll
        for (int n = 0; n < 7; ++n) {
            float a = 0.f;
            #pragma unroll
            for (int m = 0; m < 7; ++m) a = fmaf(rdl(adjr, n * 7 + m), e[m], a);
            unsigned short h, l; hsplit(a, h, l);
            aw[n * 64 + lane] = h; aw[448 + n * 64 + lane] = l;
        }
        WFENCE();
        // ---- gcn1 MFMA ----
        {
            s8v ah0 = *(const s8v*)(aw + c15 * 64 + q * 8);
            s8v ah1 = *(const s8v*)(aw + c15 * 64 + 32 + q * 8);
            s8v al0 = *(const s8v*)(aw + 448 + c15 * 64 + q * 8);
            s8v al1 = *(const s8v*)(aw + 448 + c15 * 64 + 32 + q * 8);
            ll64 a80 = pk8(ah0), a81 = pk8(ah1);
            f4v res[4];
            #pragma unroll
            for (int nt = 0; nt < 4; ++nt) {
                s8v wh0 = CHIv[(nt * 2 + 0) * 64 + lane];
                s8v wh1 = CHIv[(nt * 2 + 1) * 64 + lane];
                ll64 wl0 = *(const ll64*)(CLO + (nt * 2 + 0) * 512 + lane * 8);
                ll64 wl1 = *(const ll64*)(CLO + (nt * 2 + 1) * 512 + lane * 8);
                f4v A = {bg1v[nt], bg1v[nt], bg1v[nt], bg1v[nt]};
                f4v B = {0.f, 0.f, 0.f, 0.f};
                A = mfmah(ah0, wh0, A); A = mfmah(ah1, wh1, A);
                B = mfmah(al0, wh0, B); B = mfmah(al1, wh1, B);
                B = mfma8(a80, wl0, B); B = mfma8(a81, wl1, B);
                res[nt] = A + B * INV2048;
            }
            #pragma unroll
            for (int nt = 0; nt < 4; ++nt) {
                #pragma unroll
                for (int r = 0; r < 4; ++r) {
                    int m = q * 4 + r;
                    float v = fmaxf(res[nt][r], 0.0f);
                    if (m < 7) {
                        unsigned short h, l; hsplit(v, h, l);
                        aw[m * 64 + nt * 16 + c15] = h; aw[448 + m * 64 + nt * 16 + c15] = l;
                    }
                }
            }
        }
        WFENCE();
        // ---- readback s1; mix2; store ae2 ----
        float s1[7];
        #pragma unroll
        for (int n = 0; n < 7; ++n) s1[n] = hjoin(aw[n * 64 + lane], aw[448 + n * 64 + lane]);
        #pragma unroll
        for (int n = 0; n < 7; ++n) {
            float a = 0.f;
            #pragma unroll
            for (int m = 0; m < 7; ++m) a = fmaf(rdl(adjr, n * 7 + m), s1[m], a);
            unsigned short h, l; hsplit(a, h, l);
            aw[n * 64 + lane] = h; aw[448 + n * 64 + lane] = l;
        }
        WFENCE();
        // ---- gcn2 MFMA ----
        {
            s8v ah0 = *(const s8v*)(aw + c15 * 64 + q * 8);
            s8v ah1 = *(const s8v*)(aw + c15 * 64 + 32 + q * 8);
            s8v al0 = *(const s8v*)(aw + 448 + c15 * 64 + q * 8);
            s8v al1 = *(const s8v*)(aw + 448 + c15 * 64 + 32 + q * 8);
            ll64 a80 = pk8(ah0), a81 = pk8(ah1);
            f4v res[4];
            #pragma unroll
            for (int nt = 0; nt < 4; ++nt) {
                s8v wh0 = CHIv[(8 + nt * 2 + 0) * 64 + lane];
                s8v wh1 = CHIv[(8 + nt * 2 + 1) * 64 + lane];
                ll64 wl0 = *(const ll64*)(CLO + (8 + nt * 2 + 0) * 512 + lane * 8);
                ll64 wl1 = *(const ll64*)(CLO + (8 + nt * 2 + 1) * 512 + lane * 8);
                f4v A = {bg2v[nt], bg2v[nt], bg2v[nt], bg2v[nt]};
                f4v B = {0.f, 0.f, 0.f, 0.f};
                A = mfmah(ah0, wh0, A); A = mfmah(ah1, wh1, A);
                B = mfmah(al0, wh0, B); B = mfmah(al1, wh1, B);
                B = mfma8(a80, wl0, B); B = mfma8(a81, wl1, B);
                res[nt] = A + B * INV2048;
            }
            #pragma unroll
            for (int nt = 0; nt < 4; ++nt) {
                #pragma unroll
                for (int r = 0; r < 4; ++r) {
                    int m = q * 4 + r;
                    float v = fmaxf(res[nt][r], 0.0f);
                    if (m < 7) {
                        unsigned short h, l; hsplit(v, h, l);
                        aw[m * 64 + nt * 16 + c15] = h; aw[448 + m * 64 + nt * 16 + c15] = l;
                    }
                }
            }
        }
        WFENCE();
        // ---- gates MFMA, hb-major with FULLY STATIC indexing ----
        // R8 bug (fixed): `#pragma unroll 4` made gacc[nt] runtime-indexed -> the
        // compiler demoted the accumulator array to scratch (4.7 GB HBM write storm).
        // Now: for each 16-col h-block, compute i/f/g/o tiles into 4 register f4vs
        // and immediately run the pointwise. Max 4 live accumulators, zero scratch.
        {
            s8v s2h0 = *(const s8v*)(aw + c15 * 64 + q * 8);
            s8v s2h1 = *(const s8v*)(aw + c15 * 64 + 32 + q * 8);
            s8v s2l0 = *(const s8v*)(aw + 448 + c15 * 64 + q * 8);
            s8v s2l1 = *(const s8v*)(aw + 448 + c15 * 64 + 32 + q * 8);
            s8v hxh0 = *(const s8v*)(aw + 896 + c15 * 64 + q * 8);
            s8v hxh1 = *(const s8v*)(aw + 896 + c15 * 64 + 32 + q * 8);
            s8v hxl0 = *(const s8v*)(aw + 1344 + c15 * 64 + q * 8);
            s8v hxl1 = *(const s8v*)(aw + 1344 + c15 * 64 + 32 + q * 8);
            ll64 s280 = pk8(s2h0), s281 = pk8(s2h1);
            ll64 hx80 = pk8(hxh0), hx81 = pk8(hxh1);
            #pragma unroll
            for (int hb = 0; hb < 4; ++hb) {
                f4v gv[4];
                #pragma unroll
                for (int gi = 0; gi < 4; ++gi) {
                    const int nt = gi * 4 + hb;       // gate gi, h-block hb
                    const int fb = nt * 4;
                    s8v wi0 = GHIv[(fb + 0) * 64 + lane];
                    s8v wi1 = GHIv[(fb + 1) * 64 + lane];
                    s8v wh0 = GHIv[(fb + 2) * 64 + lane];
                    s8v wh1 = GHIv[(fb + 3) * 64 + lane];
                    ll64 li0 = *(const ll64*)(GLO + (fb + 0) * 512 + lane * 8);
                    ll64 li1 = *(const ll64*)(GLO + (fb + 1) * 512 + lane * 8);
                    ll64 lh0 = *(const ll64*)(GLO + (fb + 2) * 512 + lane * 8);
                    ll64 lh1 = *(const ll64*)(GLO + (fb + 3) * 512 + lane * 8);
                    f4v A = {biasg[nt], biasg[nt], biasg[nt], biasg[nt]};
                    f4v B = {0.f, 0.f, 0.f, 0.f};
                    A = mfmah(s2h0, wi0, A); A = mfmah(s2h1, wi1, A);
                    A = mfmah(hxh0, wh0, A); A = mfmah(hxh1, wh1, A);
                    B = mfmah(s2l0, wi0, B); B = mfmah(s2l1, wi1, B);
                    B = mfmah(hxl0, wh0, B); B = mfmah(hxl1, wh1, B);
                    B = mfma8(s280, li0, B); B = mfma8(s281, li1, B);
                    B = mfma8(hx80, lh0, B); B = mfma8(hx81, lh1, B);
                    gv[gi] = A + B * INV2048;
                }
                // pointwise for columns hb*16+c15
                #pragma unroll
                for (int r = 0; r < 4; ++r) {
                    float iv = fsigm(gv[0][r]);
                    float fv = fsigm(gv[1][r]);
                    float gg = ftanh_(gv[2][r]);
                    float ov = fsigm(gv[3][r]);
                    float cc = fmaf(fv, cx[hb * 4 + r], iv * gg);
                    cx[hb * 4 + r] = cc;
                    float hh = ov * ftanh_(cc);
                    int m = q * 4 + r;
                    if (m < 7) {
                        unsigned short h, l; hsplit(hh, h, l);
                        aw[896 + m * 64 + hb * 16 + c15] = h;
                        aw[1344 + m * 64 + hb * 16 + c15] = l;
                    }
                }
            }
        }
        WFENCE();
    };

    // ---- history scan ----
    const float* xb = xh + (size_t)batch * 1848;
    #pragma unroll 1
    for (int t = 0; t < 24; ++t) {
        xr0 = xb[t * 77 + lane];
        xr1 = (lane < 13) ? xb[t * 77 + 64 + lane] : 0.0f;
        cell();
    }
    gapf[lane] = xr0;
    if (lane < 13) gapf[64 + lane] = xr1;
    WFENCE();

    // ---- autoregressive future scan ----
    float* outb = out + (size_t)batch * 2016;
    #pragma unroll 1
    for (int st = 0; st < 48; ++st) {
        cell();
        // dec1 MFMA (hi + act-lo cross): d1 -> fp32 stride-33 in own float view
        {
            s8v hxh0 = *(const s8v*)(aw + 896 + c15 * 64 + q * 8);
            s8v hxh1 = *(const s8v*)(aw + 896 + c15 * 64 + 32 + q * 8);
            s8v hxl0 = *(const s8v*)(aw + 1344 + c15 * 64 + q * 8);
            s8v hxl1 = *(const s8v*)(aw + 1344 + c15 * 64 + 32 + q * 8);
            #pragma unroll
            for (int nt = 0; nt < 2; ++nt) {
                s8v wh0 = DHIv[(nt * 2 + 0) * 64 + lane];
                s8v wh1 = DHIv[(nt * 2 + 1) * 64 + lane];
                f4v A = {bdec[nt], bdec[nt], bdec[nt], bdec[nt]};
                f4v B = {0.f, 0.f, 0.f, 0.f};
                A = mfmah(hxh0, wh0, A); A = mfmah(hxh1, wh1, A);
                B = mfmah(hxl0, wh0, B); B = mfmah(hxl1, wh1, B);
                f4v res = A + B * INV2048;
                #pragma unroll
                for (int r = 0; r < 4; ++r) {
                    int m = q * 4 + r;
                    if (m < 7) fw[m * 33 + nt * 16 + c15] = fmaxf(res[r], 0.0f);
                }
            }
        }
        WFENCE();
        // dec2 + residual + clip + store
        if (lane < 42) {
            float a = bd2;
            #pragma unroll 8
            for (int jj = 0; jj < 32; ++jj)
                a = fmaf(fw[dn * 33 + jj], d2wL[jj * 6 + dd], a);
            float p = gapf[dn * 11 + dd] + ftanh_(a) * 0.05f;
            p = fminf(fmaxf(p, 0.0f), 1.0f);
            gapf[dn * 11 + dd] = p;
            outb[st * 42 + lane] = p;
        }
        WFENCE();
        if (u0) xr0 = gapf[lane];
        if (u1) xr1 = gapf[64 + lane];
    }
}

extern "C" void kernel_launch(void* const* d_in, const int* in_sizes, int n_in,
                              void* d_out, int out_size, void* d_ws, size_t ws_size,
                              hipStream_t stream)
{
    const float* xh   = (const float*)d_in[0];
    const float* adjp = (const float*)d_in[1];
    const float* encw = (const float*)d_in[2];
    const float* encb = (const float*)d_in[3];
    const float* g1w  = (const float*)d_in[4];
    const float* g1b  = (const float*)d_in[5];
    const float* g2w  = (const float*)d_in[6];
    const float* g2b  = (const float*)d_in[7];
    const float* wih  = (const float*)d_in[8];
    const float* whh  = (const float*)d_in[9];
    const float* bih  = (const float*)d_in[10];
    const float* bhh  = (const float*)d_in[11];
    const float* d1w  = (const float*)d_in[12];
    const float* d1b  = (const float*)d_in[13];
    const float* d2w  = (const float*)d_in[14];
    const float* d2b  = (const float*)d_in[15];
    float* out = (float*)d_out;
    unsigned char* ws = (unsigned char*)d_ws;

    hipLaunchKernelGGL(build_ws, dim3(1), dim3(256), 0, stream, g1w, g2w, d1w, wih, whh, ws);
    hipLaunchKernelGGL(stgnn, dim3(512), dim3(512), 0, stream,
                       xh, adjp, encw, encb, g1b, g2b, bih, bhh,
                       d1b, d2w, d2b, (const unsigned char*)ws, out);
}